// Round 11
// baseline (10195.328 us; speedup 1.0000x reference)
//
#include <hip/hip_runtime.h>
#include <math.h>

#define H    1024
#define C    151
#define E    200
#define DIN  2048
#define T    32
#define B    128
#define SIXH  (6*H)   // 6144
#define FIVEH (5*H)   // 5120
#define KTOT  DIN     // 2048
#define NEMB  (C+1)   // 152
#define NWGF  256     // fused grid: 256 WGs, each owns 4 j-cols x 5 gates = 20 packed cols
#define GUARD (1 << 20)

typedef _Float16 f16x8 __attribute__((ext_vector_type(8)));
typedef _Float16 f16x4 __attribute__((ext_vector_type(4)));
typedef float    f32x4 __attribute__((ext_vector_type(4)));

#define GLOAD_LDS16(g, l) __builtin_amdgcn_global_load_lds( \
    (const __attribute__((address_space(1))) unsigned int*)(g), \
    (__attribute__((address_space(3))) unsigned int*)(l), 16, 0, 0)

// ---- flag-array grid barrier (R3/R9 verified chain), 256-WG variant ----
// Session R1-R10: per-sync cost ~24us is invariant to poll topology, dirty-L2
// volume, and surrounding work. This round halves the COUNT (2 -> 1 per step)
// via gate-aligned column ownership; the barrier itself is unchanged.
__device__ __forceinline__ void gbar(int* slots, int tid, int val) {
    __syncthreads();   // drain WG stores (vmcnt) before release RMW
    if (tid == 0)
        __hip_atomic_fetch_add(&slots[blockIdx.x * 16], 1,
                               __ATOMIC_ACQ_REL, __HIP_MEMORY_SCOPE_AGENT);
    int ok, guard = 0;
    do {
        int v = __hip_atomic_load(&slots[tid * 16],
                                  __ATOMIC_RELAXED, __HIP_MEMORY_SCOPE_AGENT);
        ok = __syncthreads_and(v >= val);
        if (!ok) __builtin_amdgcn_s_sleep(1);
    } while (!ok && ++guard < GUARD);
    __builtin_amdgcn_fence(__ATOMIC_ACQUIRE, "agent");
}

// ---------------- init: zero h, c, hhi, hlo, eidx, barrier+pred flags ----------------
__global__ void init_kernel(float* h, float* c, _Float16* hhi, _Float16* hlo,
                            int* eidx, int* bar) {
    int i = blockIdx.x * blockDim.x + threadIdx.x;
    if (i < B * H) {
        h[i] = 0.f; c[i] = 0.f;
        hhi[i] = (_Float16)0.f; hlo[i] = (_Float16)0.f;
    }
    if (i < B) eidx[i] = 0;
    if (i < 8192) bar[i] = 0;   // 256 main flags + 32 pred flags (x16 padded)
}

// ---------------- X [4096][2048] fp32 -> hi/lo fp16 (same layout) ----------------
__global__ void cvt_x(const float* __restrict__ X, _Float16* __restrict__ hi,
                      _Float16* __restrict__ lo) {
    size_t i = ((size_t)blockIdx.x * 256 + threadIdx.x) * 4;
    float4 v = *(const float4*)(X + i);
    f16x4 h, l;
    h.x = (_Float16)v.x; l.x = (_Float16)(v.x - (float)h.x);
    h.y = (_Float16)v.y; l.y = (_Float16)(v.y - (float)h.y);
    h.z = (_Float16)v.z; l.z = (_Float16)(v.z - (float)h.z);
    h.w = (_Float16)v.w; l.w = (_Float16)(v.w - (float)h.w);
    *(f16x4*)(hi + i) = h;
    *(f16x4*)(lo + i) = l;
}

// ---------------- W [KR][NC] fp32 -> out [NC][KR] hi/lo fp16 (transposed) ----------------
template<int KR, int NC>
__global__ void cvt_wT(const float* __restrict__ W, _Float16* __restrict__ hi,
                       _Float16* __restrict__ lo) {
    __shared__ float tile[32][33];
    int n0 = blockIdx.x * 32, k0 = blockIdx.y * 32;
    int tx = threadIdx.x & 31, ty = threadIdx.x >> 5;   // ty 0..7
    #pragma unroll
    for (int i = 0; i < 4; ++i) {
        int k = ty + i * 8;
        tile[k][tx] = W[(size_t)(k0 + k) * NC + n0 + tx];
    }
    __syncthreads();
    #pragma unroll
    for (int i = 0; i < 4; ++i) {
        int n = ty + i * 8;
        float v = tile[tx][n];              // = W[k0+tx][n0+n]
        _Float16 h = (_Float16)v;
        size_t o = (size_t)(n0 + n) * KR + k0 + tx;
        hi[o] = h;
        lo[o] = (_Float16)(v - (float)h);
    }
}

// ---------------- Etab[k][n] = sum_e embed[k][e] * Wi[DIN+e][n]  (fp32) ----------------
__global__ void etab_kernel(const float* __restrict__ embed,
                            const float* __restrict__ Wi,
                            float* __restrict__ Etab) {
    int n = blockIdx.x * 256 + threadIdx.x;
    int k = blockIdx.y;
    const float* wp = Wi + (size_t)DIN * SIXH + n;
    const float* ep = embed + k * E;
    float acc = 0.f;
    #pragma unroll 8
    for (int e = 0; e < E; ++e)
        acc = fmaf(ep[e], wp[(size_t)e * SIXH], acc);
    Etab[(size_t)k * SIXH + n] = acc;
}

// ---------------- P = X @ Wi_x + bi, fp16x3 MFMA. tile 128x128 ----------
__global__ __launch_bounds__(256) void big_gemm_mfma(
    const _Float16* __restrict__ Ahi, const _Float16* __restrict__ Alo,
    const _Float16* __restrict__ Bhi, const _Float16* __restrict__ Blo,
    const float* __restrict__ bi, float* __restrict__ P)
{
    __shared__ __align__(16) _Float16 sAh[128 * 32];
    __shared__ __align__(16) _Float16 sAl[128 * 32];
    __shared__ __align__(16) _Float16 sBh[128 * 32];
    __shared__ __align__(16) _Float16 sBl[128 * 32];
    const int tid = threadIdx.x;
    const int n0 = blockIdx.x * 128;
    const int m0 = blockIdx.y * 128;
    const int lane = tid & 63, w = tid >> 6;
    const int wm = (w >> 1) * 64, wn = (w & 1) * 64;
    const int lr = lane & 15, lq = lane >> 4;

    f32x4 acc[4][4];
    #pragma unroll
    for (int i = 0; i < 4; ++i)
        #pragma unroll
        for (int j = 0; j < 4; ++j)
            acc[i][j] = (f32x4){0.f, 0.f, 0.f, 0.f};

    const int row0 = tid >> 2;
    const int kc = tid & 3;
    const int kcs = kc ^ ((row0 >> 1) & 3);
    const int sw = (lq ^ ((lr >> 1) & 3)) * 8;

    for (int k0 = 0; k0 < KTOT; k0 += 32) {
        #pragma unroll
        for (int i = 0; i < 2; ++i) {
            int row = row0 + i * 64;
            size_t ga = (size_t)(m0 + row) * KTOT + k0 + kcs * 8;
            size_t gb = (size_t)(n0 + row) * KTOT + k0 + kcs * 8;
            int loff = (i * 256 + tid) * 8;
            GLOAD_LDS16(Ahi + ga, sAh + loff);
            GLOAD_LDS16(Alo + ga, sAl + loff);
            GLOAD_LDS16(Bhi + gb, sBh + loff);
            GLOAD_LDS16(Blo + gb, sBl + loff);
        }
        __syncthreads();
        f16x8 ah[4], al[4], bh[4], bl[4];
        #pragma unroll
        for (int i = 0; i < 4; ++i) {
            ah[i] = *(const f16x8*)&sAh[(wm + i * 16 + lr) * 32 + sw];
            al[i] = *(const f16x8*)&sAl[(wm + i * 16 + lr) * 32 + sw];
            bh[i] = *(const f16x8*)&sBh[(wn + i * 16 + lr) * 32 + sw];
            bl[i] = *(const f16x8*)&sBl[(wn + i * 16 + lr) * 32 + sw];
        }
        #pragma unroll
        for (int i = 0; i < 4; ++i)
            #pragma unroll
            for (int j = 0; j < 4; ++j) {
                acc[i][j] = __builtin_amdgcn_mfma_f32_16x16x32_f16(ah[i], bh[j], acc[i][j], 0, 0, 0);
                acc[i][j] = __builtin_amdgcn_mfma_f32_16x16x32_f16(ah[i], bl[j], acc[i][j], 0, 0, 0);
                acc[i][j] = __builtin_amdgcn_mfma_f32_16x16x32_f16(al[i], bh[j], acc[i][j], 0, 0, 0);
            }
        __syncthreads();
    }
    #pragma unroll
    for (int i = 0; i < 4; ++i)
        #pragma unroll
        for (int j = 0; j < 4; ++j) {
            int gcol = n0 + wn + j * 16 + lr;
            float bv = bi[gcol];
            #pragma unroll
            for (int r = 0; r < 4; ++r) {
                int grow = m0 + wm + i * 16 + lq * 4 + r;
                P[(size_t)grow * SIXH + gcol] = acc[i][j][r] + bv;
            }
        }
}

// ---- pred for one timestep (R6-verified logic): one b per wave ----
__device__ __forceinline__ void do_pred(int tp, const float* hsrc,
                                        const float* Wo, const float* bo,
                                        const int* labels, float* dists,
                                        float* comms, int* eidx,
                                        int wg, int w, int lane) {
    const int b = wg * 4 + w;
    const float* hrow = hsrc + (size_t)b * H;
    const int c0 = lane, c1 = lane + 64, c2 = lane + 128;
    float a0 = bo[c0];
    float a1 = (c1 < C) ? bo[c1] : 0.f;
    float a2 = (c2 < C) ? bo[c2] : 0.f;
    #pragma unroll 8
    for (int k = 0; k < H; ++k) {
        float hk = hrow[k];
        const float* wr = Wo + (size_t)k * C;
        a0 = fmaf(hk, wr[c0], a0);
        if (c1 < C) a1 = fmaf(hk, wr[c1], a1);
        if (c2 < C) a2 = fmaf(hk, wr[c2], a2);
    }
    float* drow = dists + ((size_t)tp * B + b) * C;
    drow[c0] = a0;
    if (c1 < C) drow[c1] = a1;
    if (c2 < C) drow[c2] = a2;
    float bv2 = -1e30f; int bi2 = 0x7fffffff;
    if (c0 >= 1) { bv2 = a0; bi2 = c0; }
    if (c1 < C && (a1 > bv2 || (a1 == bv2 && c1 < bi2))) { bv2 = a1; bi2 = c1; }
    if (c2 < C && (a2 > bv2 || (a2 == bv2 && c2 < bi2))) { bv2 = a2; bi2 = c2; }
    #pragma unroll
    for (int s = 32; s > 0; s >>= 1) {
        float v2 = __shfl_down(bv2, s, 64);
        int   i2 = __shfl_down(bi2, s, 64);
        if (v2 > bv2 || (v2 == bv2 && i2 < bi2)) { bv2 = v2; bi2 = i2; }
    }
    if (lane == 0) {
        int lt = labels[tp * B + b];
        int comm = (lt == 0) ? bi2 : lt;
        comms[tp * B + b] = (float)comm;
        // coherent store: gate WGs read via agent-relaxed load at coherence point
        __hip_atomic_store(&eidx[b], comm + 1, __ATOMIC_RELAXED, __HIP_MEMORY_SCOPE_AGENT);
    }
}

// ================= persistent fused loop: ONE barrier per step =================
// 256 WGs, each owns jset = {wg*4..wg*4+3}; packed GEMM cols c = k_gate*4 + jj
// (20 cols, padded to 32 in LDS). ps lives only in acc->psL (LDS) -> gate is
// local, no second barrier. h double-buffered by parity (A=even steps, B=odd;
// B = legacy zero-init buffer read at t=0). Pred for step t-1 runs at the top
// of step t on WGs 0-31 (one b per wave), overlapped with everyone's GEMM;
// gates poll 32 pred flags (likely pre-satisfied) + coherent eidx loads.
__global__ __launch_bounds__(256, 1) void fused_loop(
    const float* __restrict__ P,
    const float* __restrict__ Etab,
    const float* __restrict__ bs,
    const _Float16* __restrict__ WsThi,
    const _Float16* __restrict__ WsTlo,
    _Float16* __restrict__ hhiA, _Float16* __restrict__ hloA,   // parity 0 (overlay)
    _Float16* __restrict__ hhiB, _Float16* __restrict__ hloB,   // parity 1 (legacy, zeroed)
    float* __restrict__ hfpA, float* __restrict__ hfpB,         // fp32 h for pred
    const float* __restrict__ Wo,
    const float* __restrict__ bo,
    const int* __restrict__ labels,
    float* __restrict__ dists,
    float* __restrict__ comms,
    int* __restrict__ eidx,
    int* bar)
{
    __shared__ __align__(16) _Float16 sBh[32 * 1024];   // 64 KB packed Ws hi (XOR-swizzled)
    __shared__ __align__(16) _Float16 sBl[32 * 1024];   // 64 KB packed Ws lo
    __shared__ __align__(16) float psL[128][20];        // 10 KB ps bounce (row = 80B, 16B-mult)

    const int wg  = blockIdx.x;
    const int tid = threadIdx.x;
    const int lane = tid & 63, w = tid >> 6;
    const int lr = lane & 15, lq = lane >> 4;
    const int mrow0 = w * 32;
    int* mainf = bar;                 // 256 slots x16
    int* predf = bar + NWGF * 16;     // 32 slots x16

    // ---- stage packed Ws slice: col c<20 <- WsT row (c>>2)*H + wg*4 + (c&3); c>=20 zero ----
    for (int gi = tid; gi < 32 * 128; gi += 256) {
        int c  = gi >> 7;           // packed col 0..31
        int kg = gi & 127;          // 16B granule
        int dst = (c * 2048 + kg * 16) ^ ((c & 7) << 4);   // bytes, same swizzle as R9
        f16x8 vh, vl;
        #pragma unroll
        for (int q = 0; q < 8; ++q) { vh[q] = (_Float16)0.f; vl[q] = (_Float16)0.f; }
        if (c < 20) {
            size_t n = (size_t)(c >> 2) * H + wg * 4 + (c & 3);
            vh = *(const f16x8*)&WsThi[n * H + kg * 8];
            vl = *(const f16x8*)&WsTlo[n * H + kg * 8];
        }
        *(f16x8*)((char*)sBh + dst) = vh;
        *(f16x8*)((char*)sBl + dst) = vl;
    }

    // gate state: tid<128 handles b=tid, all 4 jj of this WG's jset
    float creg[4] = {0.f, 0.f, 0.f, 0.f};
    f32x4 bsv4[5];
    if (tid < B) {
        #pragma unroll
        for (int k = 0; k < 5; ++k)
            bsv4[k] = *(const f32x4*)&bs[k * H + wg * 4];
    }
    __syncthreads();

    int bval = 0;
    for (int t = 0; t < T; ++t) {
        // ---- pred(t-1) on WGs 0-31, overlapped with all WGs' GEMM ----
        if (wg < 32 && t > 0) {
            const float* hsrc = ((t - 1) & 1) ? hfpB : hfpA;
            do_pred(t - 1, hsrc, Wo, bo, labels, dists, comms, eidx, wg, w, lane);
            __syncthreads();   // drain eidx/dists stores before flag release
            if (tid == 0)
                __hip_atomic_fetch_add(&predf[wg * 16], 1,
                                       __ATOMIC_ACQ_REL, __HIP_MEMORY_SCOPE_AGENT);
        }

        // ---- P prefetch for gate (addresses known now; resolves under GEMM) ----
        f32x4 pf4[6];
        if (tid < B) {
            const float* prow = P + ((size_t)t * B + tid) * SIXH + wg * 4;
            #pragma unroll
            for (int k = 0; k < 6; ++k)
                pf4[k] = *(const f32x4*)&prow[k * H];
        }

        // ---- GEMM: acc = h(t-1) @ packed-Ws, fp16x3 (R9-verified loop shape) ----
        const _Float16* rhh = (t & 1) ? hhiA : hhiB;
        const _Float16* rhl = (t & 1) ? hloA : hloB;
        f32x4 acc[2][2];
        #pragma unroll
        for (int i = 0; i < 2; ++i)
            #pragma unroll
            for (int j = 0; j < 2; ++j)
                acc[i][j] = (f32x4){0.f, 0.f, 0.f, 0.f};

        #pragma unroll 4
        for (int k0 = 0; k0 < H; k0 += 32) {
            f16x8 ah[2], al[2], bh[2], bl[2];
            #pragma unroll
            for (int i = 0; i < 2; ++i) {
                size_t ho = (size_t)(mrow0 + i * 16 + lr) * H + k0 + lq * 8;
                ah[i] = *(const f16x8*)&rhh[ho];
                al[i] = *(const f16x8*)&rhl[ho];
            }
            #pragma unroll
            for (int j = 0; j < 2; ++j) {
                int col = j * 16 + lr;
                int off = (col * 2048 + (k0 + lq * 8) * 2) ^ ((col & 7) << 4);
                bh[j] = *(const f16x8*)((const char*)sBh + off);
                bl[j] = *(const f16x8*)((const char*)sBl + off);
            }
            #pragma unroll
            for (int i = 0; i < 2; ++i)
                #pragma unroll
                for (int j = 0; j < 2; ++j) {
                    acc[i][j] = __builtin_amdgcn_mfma_f32_16x16x32_f16(ah[i], bh[j], acc[i][j], 0, 0, 0);
                    acc[i][j] = __builtin_amdgcn_mfma_f32_16x16x32_f16(ah[i], bl[j], acc[i][j], 0, 0, 0);
                    acc[i][j] = __builtin_amdgcn_mfma_f32_16x16x32_f16(al[i], bh[j], acc[i][j], 0, 0, 0);
                }
        }
        // acc -> psL (cols < 20 only; identical bits to the old global-ps path)
        #pragma unroll
        for (int i = 0; i < 2; ++i)
            #pragma unroll
            for (int j = 0; j < 2; ++j) {
                int col = j * 16 + lr;
                if (col < 20) {
                    #pragma unroll
                    for (int r = 0; r < 4; ++r)
                        psL[mrow0 + i * 16 + lq * 4 + r][col] = acc[i][j][r];
                }
            }
        __syncthreads();   // psL visible WG-wide

        // ---- poll pred flags >= t (pre-satisfied in steady state; no fence:
        // eidx is read via coherent agent-relaxed loads below) ----
        {
            int ok, guard = 0;
            do {
                int v = t;
                if (tid < 32)
                    v = __hip_atomic_load(&predf[tid * 16],
                                          __ATOMIC_RELAXED, __HIP_MEMORY_SCOPE_AGENT);
                ok = __syncthreads_and(v >= t);
                if (!ok) __builtin_amdgcn_s_sleep(1);
            } while (!ok && ++guard < GUARD);
        }

        // ---- gate: local, tid<128, b=tid, 4 jj per thread ----
        if (tid < B) {
            const int b = tid;
            int ei = __hip_atomic_load(&eidx[b], __ATOMIC_RELAXED, __HIP_MEMORY_SCOPE_AGENT);
            const float* erow = Etab + (size_t)ei * SIXH + wg * 4;
            f32x4 er[6];
            #pragma unroll
            for (int k = 0; k < 6; ++k)
                er[k] = *(const f32x4*)&erow[k * H];
            f32x4 pq[5];
            #pragma unroll
            for (int k = 0; k < 5; ++k)
                pq[k] = *(const f32x4*)&psL[b][k * 4];
            f32x4 hnv;
            f16x4 phv, plv;
            #pragma unroll
            for (int jj = 0; jj < 4; ++jj) {
                float gv[5];
                #pragma unroll
                for (int k = 0; k < 5; ++k)
                    gv[k] = pf4[k][jj] + er[k][jj] + pq[k][jj] + bsv4[k][jj];
                float pi5 = pf4[5][jj] + er[5][jj];
                float ig = 1.f / (1.f + expf(-gv[0]));
                float fg = 1.f / (1.f + expf(-gv[1]));
                float mi = tanhf(gv[2]);
                float og = 1.f / (1.f + expf(-gv[3]));
                float hw2 = 1.f / (1.f + expf(-gv[4]));
                float cn = ig * mi + fg * creg[jj];
                float out = og * tanhf(cn);
                float hn = hw2 * out + (1.f - hw2) * pi5;
                creg[jj] = cn;
                hnv[jj] = hn;
                _Float16 hh = (_Float16)hn;
                phv[jj] = hh;
                plv[jj] = (_Float16)(hn - (float)hh);
            }
            _Float16* whh = (t & 1) ? hhiB : hhiA;
            _Float16* whl = (t & 1) ? hloB : hloA;
            float*    wfp = (t & 1) ? hfpB : hfpA;
            *(f16x4*)&whh[(size_t)b * H + wg * 4] = phv;
            *(f16x4*)&whl[(size_t)b * H + wg * 4] = plv;
            *(f32x4*)&wfp[(size_t)b * H + wg * 4] = hnv;
        }

        // ---- single grid barrier per step: h(t) exchange ----
        ++bval;
        gbar(mainf, tid, bval);
    }

    // ---- final pred(T-1): outputs only, nobody waits on it ----
    if (wg < 32) {
        const float* hsrc = ((T - 1) & 1) ? hfpB : hfpA;
        do_pred(T - 1, hsrc, Wo, bo, labels, dists, comms, eidx, wg, w, lane);
    }
}

// ================= fallback per-timestep kernels (used only if coop launch fails) =====
__global__ __launch_bounds__(256) void ps_mfma(
    const _Float16* __restrict__ Ahi, const _Float16* __restrict__ Alo,
    const _Float16* __restrict__ Bhi, const _Float16* __restrict__ Blo,
    float* __restrict__ ps)
{
    __shared__ __align__(16) _Float16 sAh[64 * 32];
    __shared__ __align__(16) _Float16 sAl[64 * 32];
    __shared__ __align__(16) _Float16 sBh[64 * 32];
    __shared__ __align__(16) _Float16 sBl[64 * 32];
    const int tid = threadIdx.x;
    const int n0 = blockIdx.x * 64;
    const int m0 = blockIdx.y * 64;
    const int lane = tid & 63, w = tid >> 6;
    const int wm = (w >> 1) * 32, wn = (w & 1) * 32;
    const int lr = lane & 15, lq = lane >> 4;

    f32x4 acc[2][2];
    #pragma unroll
    for (int i = 0; i < 2; ++i)
        #pragma unroll
        for (int j = 0; j < 2; ++j)
            acc[i][j] = (f32x4){0.f, 0.f, 0.f, 0.f};

    const int row = tid >> 2;
    const int kc = tid & 3;

    for (int k0 = 0; k0 < H; k0 += 32) {
        size_t ga = (size_t)(m0 + row) * H + k0 + kc * 8;
        size_t gb = (size_t)(n0 + row) * H + k0 + kc * 8;
        int loff = tid * 8;
        GLOAD_LDS16(Ahi + ga, sAh + loff);
        GLOAD_LDS16(Alo + ga, sAl + loff);
        GLOAD_LDS16(Bhi + gb, sBh + loff);
        GLOAD_LDS16(Blo + gb, sBl + loff);
        __syncthreads();
        f16x8 ah[2], al[2], bh[2], bl[2];
        #pragma unroll
        for (int i = 0; i < 2; ++i) {
            ah[i] = *(const f16x8*)&sAh[(wm + i * 16 + lr) * 32 + lq * 8];
            al[i] = *(const f16x8*)&sAl[(wm + i * 16 + lr) * 32 + lq * 8];
            bh[i] = *(const f16x8*)&sBh[(wn + i * 16 + lr) * 32 + lq * 8];
            bl[i] = *(const f16x8*)&sBl[(wn + i * 16 + lr) * 32 + lq * 8];
        }
        #pragma unroll
        for (int i = 0; i < 2; ++i)
            #pragma unroll
            for (int j = 0; j < 2; ++j) {
                acc[i][j] = __builtin_amdgcn_mfma_f32_16x16x32_f16(ah[i], bh[j], acc[i][j], 0, 0, 0);
                acc[i][j] = __builtin_amdgcn_mfma_f32_16x16x32_f16(ah[i], bl[j], acc[i][j], 0, 0, 0);
                acc[i][j] = __builtin_amdgcn_mfma_f32_16x16x32_f16(al[i], bh[j], acc[i][j], 0, 0, 0);
            }
        __syncthreads();
    }
    #pragma unroll
    for (int i = 0; i < 2; ++i)
        #pragma unroll
        for (int j = 0; j < 2; ++j) {
            int gcol = n0 + wn + j * 16 + lr;
            #pragma unroll
            for (int r = 0; r < 4; ++r) {
                int grow = m0 + wm + i * 16 + lq * 4 + r;
                ps[(size_t)grow * FIVEH + gcol] = acc[i][j][r];
            }
        }
}

__global__ void gate_kernel(const float* __restrict__ P,
                            const float* __restrict__ Etab,
                            const float* __restrict__ ps,
                            const float* __restrict__ bs,
                            const int* __restrict__ eidx,
                            float* __restrict__ h,
                            float* __restrict__ c,
                            _Float16* __restrict__ hhi,
                            _Float16* __restrict__ hlo,
                            int t) {
    int j = blockIdx.x * 256 + threadIdx.x;
    int b = blockIdx.y;
    const float* prow = P + (size_t)(t * B + b) * SIXH;
    const float* erow = Etab + (size_t)eidx[b] * SIXH;
    const float* psr  = ps + (size_t)b * FIVEH;
    float g[5];
    #pragma unroll
    for (int k = 0; k < 5; ++k) {
        int col = k * H + j;
        g[k] = prow[col] + erow[col] + psr[col] + bs[col];
    }
    float pi5 = prow[5 * H + j] + erow[5 * H + j];
    float ig = 1.f / (1.f + expf(-g[0]));
    float fg = 1.f / (1.f + expf(-g[1]));
    float mi = tanhf(g[2]);
    float og = 1.f / (1.f + expf(-g[3]));
    float hw = 1.f / (1.f + expf(-g[4]));
    float cv = c[b * H + j];
    float cn = ig * mi + fg * cv;
    float out = og * tanhf(cn);
    float hn = hw * out + (1.f - hw) * pi5;
    c[b * H + j] = cn;
    h[b * H + j] = hn;
    _Float16 hh = (_Float16)hn;
    hhi[b * H + j] = hh;
    hlo[b * H + j] = (_Float16)(hn - (float)hh);
}

__global__ void pred_kernel(const float* __restrict__ h,
                            const float* __restrict__ Wo,
                            const float* __restrict__ bo,
                            const int* __restrict__ labels,
                            float* __restrict__ dists,
                            float* __restrict__ comms,
                            int* __restrict__ eidx,
                            int t) {
    __shared__ float hsb[H];
    __shared__ float vals[256];
    __shared__ int   idxs[256];
    int tid = threadIdx.x;
    int b = blockIdx.x;
    for (int i = tid; i < H / 4; i += 256)
        *(float4*)&hsb[i * 4] = *(const float4*)&h[b * H + i * 4];
    __syncthreads();
    float pred = 0.f;
    if (tid < C) {
        pred = bo[tid];
        #pragma unroll 8
        for (int k = 0; k < H; ++k)
            pred = fmaf(hsb[k], Wo[k * C + tid], pred);
        dists[(size_t)(t * B + b) * C + tid] = pred;
    }
    vals[tid] = (tid >= 1 && tid < C) ? pred : -1e30f;
    idxs[tid] = tid;
    __syncthreads();
    for (int s = 128; s > 0; s >>= 1) {
        if (tid < s) {
            float v2 = vals[tid + s];
            int   i2 = idxs[tid + s];
            if (v2 > vals[tid] || (v2 == vals[tid] && i2 < idxs[tid])) {
                vals[tid] = v2;
                idxs[tid] = i2;
            }
        }
        __syncthreads();
    }
    if (tid == 0) {
        int nzp = idxs[0];
        int lt = labels[t * B + b];
        int comm = (lt == 0) ? nzp : lt;
        comms[t * B + b] = (float)comm;
        eidx[b] = comm + 1;
    }
}

extern "C" void kernel_launch(void* const* d_in, const int* in_sizes, int n_in,
                              void* d_out, int out_size, void* d_ws, size_t ws_size,
                              hipStream_t stream) {
    const float* X      = (const float*)d_in[0];
    const int*   labels = (const int*)  d_in[1];
    const float* embed  = (const float*)d_in[2];
    const float* Wi     = (const float*)d_in[3];
    const float* bi     = (const float*)d_in[4];
    const float* Ws     = (const float*)d_in[5];
    const float* bs     = (const float*)d_in[6];
    const float* Wo     = (const float*)d_in[7];
    const float* bo     = (const float*)d_in[8];

    // R3-verified footprint + 16 KB (bar grows to 32 KB). New h-parity/hfp
    // buffers overlay dead Xlo space (Xlo only read by big_gemm).
    char* w = (char*)d_ws;
    float* P      = (float*)w;              w += (size_t)T * B * SIXH * 4;      // 100.7 MB
    float* Etab   = (float*)w;              w += (size_t)NEMB * SIXH * 4;       //   3.7 MB
    float* ps     = (float*)w;              w += (size_t)B * FIVEH * 4;         //   2.6 MB (fallback)
    float* h      = (float*)w;              w += (size_t)B * H * 4;             // fallback
    float* c      = (float*)w;              w += (size_t)B * H * 4;             // fallback
    _Float16* hhi = (_Float16*)w;           w += (size_t)B * H * 2;             // parity-1 (zeroed)
    _Float16* hlo = (_Float16*)w;           w += (size_t)B * H * 2;
    int* eidx     = (int*)w;                w += 512;
    int* bar      = (int*)w;                w += 32768;                          // 256+32 flags x16 ints
    _Float16* Xhi = (_Float16*)w;           w += (size_t)T * B * KTOT * 2;      //  16.8 MB
    _Float16* Xlo = (_Float16*)w;           w += (size_t)T * B * KTOT * 2;      //  16.8 MB
    _Float16* WiThi = (_Float16*)w;         w += (size_t)SIXH * KTOT * 2;       //  25.2 MB
    _Float16* WiTlo = (_Float16*)w;         w += (size_t)SIXH * KTOT * 2;
    _Float16* WsThi = (_Float16*)w;         w += (size_t)FIVEH * H * 2;         //  10.5 MB
    _Float16* WsTlo = (_Float16*)w;         w += (size_t)FIVEH * H * 2;
    // overlay (1.5 MB in dead 16.8 MB Xlo; write-before-read inside fused_loop)
    _Float16* hhiA = (_Float16*)Xlo;
    _Float16* hloA = hhiA + (size_t)B * H;
    float* hfpA    = (float*)(hloA + (size_t)B * H);
    float* hfpB    = hfpA + (size_t)B * H;

    float* dists = (float*)d_out;
    float* comms = dists + (size_t)T * B * C;

    init_kernel<<<512, 256, 0, stream>>>(h, c, hhi, hlo, eidx, bar);
    cvt_x<<<(T * B * KTOT) / (256 * 4), 256, 0, stream>>>(X, Xhi, Xlo);
    cvt_wT<KTOT, SIXH><<<dim3(SIXH / 32, KTOT / 32), 256, 0, stream>>>(Wi, WiThi, WiTlo);
    cvt_wT<H, FIVEH><<<dim3(FIVEH / 32, H / 32), 256, 0, stream>>>(Ws, WsThi, WsTlo);
    etab_kernel<<<dim3(SIXH / 256, NEMB), 256, 0, stream>>>(embed, Wi, Etab);
    big_gemm_mfma<<<dim3(SIXH / 128, (T * B) / 128), 256, 0, stream>>>(Xhi, Xlo, WiThi, WiTlo, bi, P);

    void* args[] = {(void*)&P, (void*)&Etab, (void*)&bs, (void*)&WsThi, (void*)&WsTlo,
                    (void*)&hhiA, (void*)&hloA, (void*)&hhi, (void*)&hlo,
                    (void*)&hfpA, (void*)&hfpB, (void*)&Wo, (void*)&bo,
                    (void*)&labels, (void*)&dists, (void*)&comms,
                    (void*)&eidx, (void*)&bar};
    hipError_t err = hipLaunchCooperativeKernel((void*)fused_loop, dim3(NWGF), dim3(256),
                                                args, 0, stream);
    if (err != hipSuccess) {
        // fallback: original per-timestep loop (legacy buffers)
        for (int t = 0; t < T; ++t) {
            ps_mfma<<<dim3(FIVEH / 64, B / 64), 256, 0, stream>>>(hhi, hlo, WsThi, WsTlo, ps);
            gate_kernel<<<dim3(H / 256, B), 256, 0, stream>>>(P, Etab, ps, bs, eidx, h, c, hhi, hlo, t);
            pred_kernel<<<B, 256, 0, stream>>>(h, Wo, bo, labels, dists, comms, eidx, t);
        }
    }
}

// Round 12
// 8737.005 us; speedup vs baseline: 1.1669x; 1.1669x over previous
//
#include <hip/hip_runtime.h>
#include <math.h>

#define H    1024
#define C    151
#define E    200
#define DIN  2048
#define T    32
#define B    128
#define SIXH  (6*H)   // 6144
#define FIVEH (5*H)   // 5120
#define KTOT  DIN     // 2048
#define NEMB  (C+1)   // 152
#define NWGF  256     // fused grid: 256 WGs, each owns 4 j-cols x 5 gates = 20 packed cols
#define GUARD (1 << 20)

typedef _Float16 f16x8 __attribute__((ext_vector_type(8)));
typedef _Float16 f16x4 __attribute__((ext_vector_type(4)));
typedef float    f32x4 __attribute__((ext_vector_type(4)));

#define GLOAD_LDS16(g, l) __builtin_amdgcn_global_load_lds( \
    (const __attribute__((address_space(1))) unsigned int*)(g), \
    (__attribute__((address_space(3))) unsigned int*)(l), 16, 0, 0)

// ---- flag-array grid barrier (R3/R9 verified chain), 256-WG variant ----
__device__ __forceinline__ void gbar(int* slots, int tid, int val) {
    __syncthreads();   // drain WG stores (vmcnt) before release RMW
    if (tid == 0)
        __hip_atomic_fetch_add(&slots[blockIdx.x * 16], 1,
                               __ATOMIC_ACQ_REL, __HIP_MEMORY_SCOPE_AGENT);
    int ok, guard = 0;
    do {
        int v = __hip_atomic_load(&slots[tid * 16],
                                  __ATOMIC_RELAXED, __HIP_MEMORY_SCOPE_AGENT);
        ok = __syncthreads_and(v >= val);
        if (!ok) __builtin_amdgcn_s_sleep(1);
    } while (!ok && ++guard < GUARD);
    __builtin_amdgcn_fence(__ATOMIC_ACQUIRE, "agent");
}

// ---------------- init: zero h, c, packed hB, eidx, barrier+pred flags ----------------
__global__ void init_kernel(float* h, float* c, _Float16* hhi, _Float16* hlo,
                            int* eidx, int* bar) {
    int i = blockIdx.x * blockDim.x + threadIdx.x;
    if (i < B * H) {
        h[i] = 0.f; c[i] = 0.f;
        hhi[i] = (_Float16)0.f; hlo[i] = (_Float16)0.f;
    }
    if (i < B) eidx[i] = 0;
    if (i < 8192) bar[i] = 0;   // 256 main flags + 32 pred flags (x16 padded)
}

// ---------------- X [4096][2048] fp32 -> hi/lo fp16 (same layout) ----------------
__global__ void cvt_x(const float* __restrict__ X, _Float16* __restrict__ hi,
                      _Float16* __restrict__ lo) {
    size_t i = ((size_t)blockIdx.x * 256 + threadIdx.x) * 4;
    float4 v = *(const float4*)(X + i);
    f16x4 h, l;
    h.x = (_Float16)v.x; l.x = (_Float16)(v.x - (float)h.x);
    h.y = (_Float16)v.y; l.y = (_Float16)(v.y - (float)h.y);
    h.z = (_Float16)v.z; l.z = (_Float16)(v.z - (float)h.z);
    h.w = (_Float16)v.w; l.w = (_Float16)(v.w - (float)h.w);
    *(f16x4*)(hi + i) = h;
    *(f16x4*)(lo + i) = l;
}

// ---------------- W [KR][NC] fp32 -> out [NC][KR] hi/lo fp16 (transposed) ----------------
template<int KR, int NC>
__global__ void cvt_wT(const float* __restrict__ W, _Float16* __restrict__ hi,
                       _Float16* __restrict__ lo) {
    __shared__ float tile[32][33];
    int n0 = blockIdx.x * 32, k0 = blockIdx.y * 32;
    int tx = threadIdx.x & 31, ty = threadIdx.x >> 5;   // ty 0..7
    #pragma unroll
    for (int i = 0; i < 4; ++i) {
        int k = ty + i * 8;
        tile[k][tx] = W[(size_t)(k0 + k) * NC + n0 + tx];
    }
    __syncthreads();
    #pragma unroll
    for (int i = 0; i < 4; ++i) {
        int n = ty + i * 8;
        float v = tile[tx][n];              // = W[k0+tx][n0+n]
        _Float16 h = (_Float16)v;
        size_t o = (size_t)(n0 + n) * KR + k0 + tx;
        hi[o] = h;
        lo[o] = (_Float16)(v - (float)h);
    }
}

// ---------------- Etab[k][n] = sum_e embed[k][e] * Wi[DIN+e][n]  (fp32) ----------------
__global__ void etab_kernel(const float* __restrict__ embed,
                            const float* __restrict__ Wi,
                            float* __restrict__ Etab) {
    int n = blockIdx.x * 256 + threadIdx.x;
    int k = blockIdx.y;
    const float* wp = Wi + (size_t)DIN * SIXH + n;
    const float* ep = embed + k * E;
    float acc = 0.f;
    #pragma unroll 8
    for (int e = 0; e < E; ++e)
        acc = fmaf(ep[e], wp[(size_t)e * SIXH], acc);
    Etab[(size_t)k * SIXH + n] = acc;
}

// ---------------- P = X @ Wi_x + bi -> written in gate-aligned PT layout ----------
// PT[((t*256 + wg)*128 + b)*24 + k*4 + jj]  where wg=(gcol&1023)>>2, k=gcol>>10,
// jj=gcol&3, t=grow>>7, b=grow&127. Gate WG wg then reads ONE contiguous 12KB
// block per step (R11's 24KB-stride 16B gathers caused FETCH 825MB @85GB/s).
__global__ __launch_bounds__(256) void big_gemm_mfma(
    const _Float16* __restrict__ Ahi, const _Float16* __restrict__ Alo,
    const _Float16* __restrict__ Bhi, const _Float16* __restrict__ Blo,
    const float* __restrict__ bi, float* __restrict__ PT)
{
    __shared__ __align__(16) _Float16 sAh[128 * 32];
    __shared__ __align__(16) _Float16 sAl[128 * 32];
    __shared__ __align__(16) _Float16 sBh[128 * 32];
    __shared__ __align__(16) _Float16 sBl[128 * 32];
    const int tid = threadIdx.x;
    const int n0 = blockIdx.x * 128;
    const int m0 = blockIdx.y * 128;
    const int lane = tid & 63, w = tid >> 6;
    const int wm = (w >> 1) * 64, wn = (w & 1) * 64;
    const int lr = lane & 15, lq = lane >> 4;

    f32x4 acc[4][4];
    #pragma unroll
    for (int i = 0; i < 4; ++i)
        #pragma unroll
        for (int j = 0; j < 4; ++j)
            acc[i][j] = (f32x4){0.f, 0.f, 0.f, 0.f};

    const int row0 = tid >> 2;
    const int kc = tid & 3;
    const int kcs = kc ^ ((row0 >> 1) & 3);
    const int sw = (lq ^ ((lr >> 1) & 3)) * 8;

    for (int k0 = 0; k0 < KTOT; k0 += 32) {
        #pragma unroll
        for (int i = 0; i < 2; ++i) {
            int row = row0 + i * 64;
            size_t ga = (size_t)(m0 + row) * KTOT + k0 + kcs * 8;
            size_t gb = (size_t)(n0 + row) * KTOT + k0 + kcs * 8;
            int loff = (i * 256 + tid) * 8;
            GLOAD_LDS16(Ahi + ga, sAh + loff);
            GLOAD_LDS16(Alo + ga, sAl + loff);
            GLOAD_LDS16(Bhi + gb, sBh + loff);
            GLOAD_LDS16(Blo + gb, sBl + loff);
        }
        __syncthreads();
        f16x8 ah[4], al[4], bh[4], bl[4];
        #pragma unroll
        for (int i = 0; i < 4; ++i) {
            ah[i] = *(const f16x8*)&sAh[(wm + i * 16 + lr) * 32 + sw];
            al[i] = *(const f16x8*)&sAl[(wm + i * 16 + lr) * 32 + sw];
            bh[i] = *(const f16x8*)&sBh[(wn + i * 16 + lr) * 32 + sw];
            bl[i] = *(const f16x8*)&sBl[(wn + i * 16 + lr) * 32 + sw];
        }
        #pragma unroll
        for (int i = 0; i < 4; ++i)
            #pragma unroll
            for (int j = 0; j < 4; ++j) {
                acc[i][j] = __builtin_amdgcn_mfma_f32_16x16x32_f16(ah[i], bh[j], acc[i][j], 0, 0, 0);
                acc[i][j] = __builtin_amdgcn_mfma_f32_16x16x32_f16(ah[i], bl[j], acc[i][j], 0, 0, 0);
                acc[i][j] = __builtin_amdgcn_mfma_f32_16x16x32_f16(al[i], bh[j], acc[i][j], 0, 0, 0);
            }
        __syncthreads();
    }
    #pragma unroll
    for (int i = 0; i < 4; ++i)
        #pragma unroll
        for (int j = 0; j < 4; ++j) {
            int gcol = n0 + wn + j * 16 + lr;
            float bv = bi[gcol];
            const int wg2 = (gcol & 1023) >> 2;
            const int kk  = gcol >> 10;
            const int jj  = gcol & 3;
            #pragma unroll
            for (int r = 0; r < 4; ++r) {
                int grow = m0 + wm + i * 16 + lq * 4 + r;
                int tt = grow >> 7, bb = grow & 127;
                PT[(((size_t)tt * 256 + wg2) * 128 + bb) * 24 + kk * 4 + jj] = acc[i][j][r] + bv;
            }
        }
}

// ---- pred for one timestep: one b per wave; reads PACKED hfp [kblk][b][4] ----
__device__ __forceinline__ void do_pred(int tp, const float* hsrc,
                                        const float* Wo, const float* bo,
                                        const int* labels, float* dists,
                                        float* comms, int* eidx,
                                        int wg, int w, int lane) {
    const int b = wg * 4 + w;
    const int c0 = lane, c1 = lane + 64, c2 = lane + 128;
    float a0 = bo[c0];
    float a1 = (c1 < C) ? bo[c1] : 0.f;
    float a2 = (c2 < C) ? bo[c2] : 0.f;
    #pragma unroll 8
    for (int k = 0; k < H; ++k) {
        float hk = hsrc[((size_t)(k >> 2) * 128 + b) * 4 + (k & 3)];
        const float* wr = Wo + (size_t)k * C;
        a0 = fmaf(hk, wr[c0], a0);
        if (c1 < C) a1 = fmaf(hk, wr[c1], a1);
        if (c2 < C) a2 = fmaf(hk, wr[c2], a2);
    }
    float* drow = dists + ((size_t)tp * B + b) * C;
    drow[c0] = a0;
    if (c1 < C) drow[c1] = a1;
    if (c2 < C) drow[c2] = a2;
    float bv2 = -1e30f; int bi2 = 0x7fffffff;
    if (c0 >= 1) { bv2 = a0; bi2 = c0; }
    if (c1 < C && (a1 > bv2 || (a1 == bv2 && c1 < bi2))) { bv2 = a1; bi2 = c1; }
    if (c2 < C && (a2 > bv2 || (a2 == bv2 && c2 < bi2))) { bv2 = a2; bi2 = c2; }
    #pragma unroll
    for (int s = 32; s > 0; s >>= 1) {
        float v2 = __shfl_down(bv2, s, 64);
        int   i2 = __shfl_down(bi2, s, 64);
        if (v2 > bv2 || (v2 == bv2 && i2 < bi2)) { bv2 = v2; bi2 = i2; }
    }
    if (lane == 0) {
        int lt = labels[tp * B + b];
        int comm = (lt == 0) ? bi2 : lt;
        comms[tp * B + b] = (float)comm;
        __hip_atomic_store(&eidx[b], comm + 1, __ATOMIC_RELAXED, __HIP_MEMORY_SCOPE_AGENT);
    }
}

// ================= persistent fused loop: ONE barrier per step =================
// R11 sync structure (verified correct) with fixed layouts:
//   PT: gate-aligned contiguous (12KB/WG/step coalesced read)
//   h:  packed [kblk=256][b=128] f16x4 — gate WG wg owns kblk=wg -> writes
//       contiguous 1KB (no cross-XCD false sharing); GEMM A-fragment = two
//       coalesced 8B loads per half (lanes sweep b).
__global__ __launch_bounds__(256, 1) void fused_loop(
    const float* __restrict__ PT,
    const float* __restrict__ Etab,
    const float* __restrict__ bs,
    const _Float16* __restrict__ WsThi,
    const _Float16* __restrict__ WsTlo,
    _Float16* __restrict__ hhiA, _Float16* __restrict__ hloA,   // parity 0 (overlay), packed
    _Float16* __restrict__ hhiB, _Float16* __restrict__ hloB,   // parity 1 (legacy, zeroed), packed
    float* __restrict__ hfpA, float* __restrict__ hfpB,         // fp32 h, packed
    const float* __restrict__ Wo,
    const float* __restrict__ bo,
    const int* __restrict__ labels,
    float* __restrict__ dists,
    float* __restrict__ comms,
    int* __restrict__ eidx,
    int* bar)
{
    __shared__ __align__(16) _Float16 sBh[32 * 1024];   // 64 KB packed Ws hi (XOR-swizzled)
    __shared__ __align__(16) _Float16 sBl[32 * 1024];   // 64 KB packed Ws lo
    __shared__ __align__(16) float psL[128][20];        // 10 KB ps bounce

    const int wg  = blockIdx.x;
    const int tid = threadIdx.x;
    const int lane = tid & 63, w = tid >> 6;
    const int lr = lane & 15, lq = lane >> 4;
    const int mrow0 = w * 32;
    int* mainf = bar;
    int* predf = bar + NWGF * 16;

    // ---- stage packed Ws slice: col c<20 <- WsT row (c>>2)*H + wg*4 + (c&3) ----
    for (int gi = tid; gi < 32 * 128; gi += 256) {
        int c  = gi >> 7;
        int kg = gi & 127;
        int dst = (c * 2048 + kg * 16) ^ ((c & 7) << 4);
        f16x8 vh, vl;
        #pragma unroll
        for (int q = 0; q < 8; ++q) { vh[q] = (_Float16)0.f; vl[q] = (_Float16)0.f; }
        if (c < 20) {
            size_t n = (size_t)(c >> 2) * H + wg * 4 + (c & 3);
            vh = *(const f16x8*)&WsThi[n * H + kg * 8];
            vl = *(const f16x8*)&WsTlo[n * H + kg * 8];
        }
        *(f16x8*)((char*)sBh + dst) = vh;
        *(f16x8*)((char*)sBl + dst) = vl;
    }

    float creg[4] = {0.f, 0.f, 0.f, 0.f};
    f32x4 bsv4[5];
    if (tid < B) {
        #pragma unroll
        for (int k = 0; k < 5; ++k)
            bsv4[k] = *(const f32x4*)&bs[k * H + wg * 4];
    }
    __syncthreads();

    int bval = 0;
    for (int t = 0; t < T; ++t) {
        // ---- pred(t-1) on WGs 0-31, overlapped with all WGs' GEMM ----
        if (wg < 32 && t > 0) {
            const float* hsrc = ((t - 1) & 1) ? hfpB : hfpA;
            do_pred(t - 1, hsrc, Wo, bo, labels, dists, comms, eidx, wg, w, lane);
            __syncthreads();
            if (tid == 0)
                __hip_atomic_fetch_add(&predf[wg * 16], 1,
                                       __ATOMIC_ACQ_REL, __HIP_MEMORY_SCOPE_AGENT);
        }

        // ---- P prefetch: contiguous 12KB block per WG (96B per thread) ----
        f32x4 pf4[6];
        if (tid < B) {
            const float* prow = PT + (((size_t)t * 256 + wg) * 128 + tid) * 24;
            #pragma unroll
            for (int k = 0; k < 6; ++k)
                pf4[k] = *(const f32x4*)&prow[k * 4];
        }

        // ---- GEMM: acc = h(t-1) @ packed-Ws, fp16x3; A from packed-h ----
        const _Float16* rhh = (t & 1) ? hhiA : hhiB;
        const _Float16* rhl = (t & 1) ? hloA : hloB;
        f32x4 acc[2][2];
        #pragma unroll
        for (int i = 0; i < 2; ++i)
            #pragma unroll
            for (int j = 0; j < 2; ++j)
                acc[i][j] = (f32x4){0.f, 0.f, 0.f, 0.f};

        #pragma unroll 4
        for (int k0 = 0; k0 < H; k0 += 32) {
            f16x8 ah[2], al[2], bh[2], bl[2];
            const int kb = (k0 >> 2) + lq * 2;     // k-block of k0 + lq*8
            #pragma unroll
            for (int i = 0; i < 2; ++i) {
                int row = mrow0 + i * 16 + lr;
                union { f16x4 h4[2]; f16x8 v; } uh, ul;
                uh.h4[0] = *(const f16x4*)&rhh[((size_t)kb * 128 + row) * 4];
                uh.h4[1] = *(const f16x4*)&rhh[((size_t)(kb + 1) * 128 + row) * 4];
                ul.h4[0] = *(const f16x4*)&rhl[((size_t)kb * 128 + row) * 4];
                ul.h4[1] = *(const f16x4*)&rhl[((size_t)(kb + 1) * 128 + row) * 4];
                ah[i] = uh.v;
                al[i] = ul.v;
            }
            #pragma unroll
            for (int j = 0; j < 2; ++j) {
                int col = j * 16 + lr;
                int off = (col * 2048 + (k0 + lq * 8) * 2) ^ ((col & 7) << 4);
                bh[j] = *(const f16x8*)((const char*)sBh + off);
                bl[j] = *(const f16x8*)((const char*)sBl + off);
            }
            #pragma unroll
            for (int i = 0; i < 2; ++i)
                #pragma unroll
                for (int j = 0; j < 2; ++j) {
                    acc[i][j] = __builtin_amdgcn_mfma_f32_16x16x32_f16(ah[i], bh[j], acc[i][j], 0, 0, 0);
                    acc[i][j] = __builtin_amdgcn_mfma_f32_16x16x32_f16(ah[i], bl[j], acc[i][j], 0, 0, 0);
                    acc[i][j] = __builtin_amdgcn_mfma_f32_16x16x32_f16(al[i], bh[j], acc[i][j], 0, 0, 0);
                }
        }
        // acc -> psL (cols < 20)
        #pragma unroll
        for (int i = 0; i < 2; ++i)
            #pragma unroll
            for (int j = 0; j < 2; ++j) {
                int col = j * 16 + lr;
                if (col < 20) {
                    #pragma unroll
                    for (int r = 0; r < 4; ++r)
                        psL[mrow0 + i * 16 + lq * 4 + r][col] = acc[i][j][r];
                }
            }
        __syncthreads();

        // ---- poll pred flags >= t (pre-satisfied in steady state) ----
        {
            int ok, guard = 0;
            do {
                int v = t;
                if (tid < 32)
                    v = __hip_atomic_load(&predf[tid * 16],
                                          __ATOMIC_RELAXED, __HIP_MEMORY_SCOPE_AGENT);
                ok = __syncthreads_and(v >= t);
                if (!ok) __builtin_amdgcn_s_sleep(1);
            } while (!ok && ++guard < GUARD);
        }

        // ---- gate: local, tid<128, b=tid, 4 jj per thread; packed-h writes ----
        if (tid < B) {
            const int b = tid;
            int ei = __hip_atomic_load(&eidx[b], __ATOMIC_RELAXED, __HIP_MEMORY_SCOPE_AGENT);
            const float* erow = Etab + (size_t)ei * SIXH + wg * 4;
            f32x4 er[6];
            #pragma unroll
            for (int k = 0; k < 6; ++k)
                er[k] = *(const f32x4*)&erow[k * H];
            f32x4 pq[5];
            #pragma unroll
            for (int k = 0; k < 5; ++k)
                pq[k] = *(const f32x4*)&psL[b][k * 4];
            f32x4 hnv;
            f16x4 phv, plv;
            #pragma unroll
            for (int jj = 0; jj < 4; ++jj) {
                float gv[5];
                #pragma unroll
                for (int k = 0; k < 5; ++k)
                    gv[k] = pf4[k][jj] + er[k][jj] + pq[k][jj] + bsv4[k][jj];
                float pi5 = pf4[5][jj] + er[5][jj];
                float ig = 1.f / (1.f + expf(-gv[0]));
                float fg = 1.f / (1.f + expf(-gv[1]));
                float mi = tanhf(gv[2]);
                float og = 1.f / (1.f + expf(-gv[3]));
                float hw2 = 1.f / (1.f + expf(-gv[4]));
                float cn = ig * mi + fg * creg[jj];
                float out = og * tanhf(cn);
                float hn = hw2 * out + (1.f - hw2) * pi5;
                creg[jj] = cn;
                hnv[jj] = hn;
                _Float16 hh = (_Float16)hn;
                phv[jj] = hh;
                plv[jj] = (_Float16)(hn - (float)hh);
            }
            _Float16* whh = (t & 1) ? hhiB : hhiA;
            _Float16* whl = (t & 1) ? hloB : hloA;
            float*    wfp = (t & 1) ? hfpB : hfpA;
            *(f16x4*)&whh[((size_t)wg * 128 + b) * 4] = phv;    // contiguous per-WG region
            *(f16x4*)&whl[((size_t)wg * 128 + b) * 4] = plv;
            *(f32x4*)&wfp[((size_t)wg * 128 + b) * 4] = hnv;
        }

        // ---- single grid barrier per step: h(t) exchange ----
        ++bval;
        gbar(mainf, tid, bval);
    }

    // ---- final pred(T-1): outputs only ----
    if (wg < 32) {
        const float* hsrc = ((T - 1) & 1) ? hfpB : hfpA;
        do_pred(T - 1, hsrc, Wo, bo, labels, dists, comms, eidx, wg, w, lane);
    }
}

// ================= fallback per-timestep kernels (coop-launch failure only) =====
__global__ __launch_bounds__(256) void ps_mfma(
    const _Float16* __restrict__ Ahi, const _Float16* __restrict__ Alo,
    const _Float16* __restrict__ Bhi, const _Float16* __restrict__ Blo,
    float* __restrict__ ps)
{
    __shared__ __align__(16) _Float16 sAh[64 * 32];
    __shared__ __align__(16) _Float16 sAl[64 * 32];
    __shared__ __align__(16) _Float16 sBh[64 * 32];
    __shared__ __align__(16) _Float16 sBl[64 * 32];
    const int tid = threadIdx.x;
    const int n0 = blockIdx.x * 64;
    const int m0 = blockIdx.y * 64;
    const int lane = tid & 63, w = tid >> 6;
    const int wm = (w >> 1) * 32, wn = (w & 1) * 32;
    const int lr = lane & 15, lq = lane >> 4;

    f32x4 acc[2][2];
    #pragma unroll
    for (int i = 0; i < 2; ++i)
        #pragma unroll
        for (int j = 0; j < 2; ++j)
            acc[i][j] = (f32x4){0.f, 0.f, 0.f, 0.f};

    const int row = tid >> 2;
    const int kc = tid & 3;

    for (int k0 = 0; k0 < H; k0 += 32) {
        size_t ga = (size_t)(m0 + row) * H + k0 + kc * 8;
        size_t gb = (size_t)(n0 + row) * H + k0 + kc * 8;
        int loff = tid * 8;
        GLOAD_LDS16(Ahi + ga, sAh + loff);
        GLOAD_LDS16(Alo + ga, sAl + loff);
        GLOAD_LDS16(Bhi + gb, sBh + loff);
        GLOAD_LDS16(Blo + gb, sBl + loff);
        __syncthreads();
        f16x8 ah[2], al[2], bh[2], bl[2];
        #pragma unroll
        for (int i = 0; i < 2; ++i) {
            ah[i] = *(const f16x8*)&sAh[(wm + i * 16 + lr) * 32 + lq * 8];
            al[i] = *(const f16x8*)&sAl[(wm + i * 16 + lr) * 32 + lq * 8];
            bh[i] = *(const f16x8*)&sBh[(wn + i * 16 + lr) * 32 + lq * 8];
            bl[i] = *(const f16x8*)&sBl[(wn + i * 16 + lr) * 32 + lq * 8];
        }
        #pragma unroll
        for (int i = 0; i < 2; ++i)
            #pragma unroll
            for (int j = 0; j < 2; ++j) {
                acc[i][j] = __builtin_amdgcn_mfma_f32_16x16x32_f16(ah[i], bh[j], acc[i][j], 0, 0, 0);
                acc[i][j] = __builtin_amdgcn_mfma_f32_16x16x32_f16(ah[i], bl[j], acc[i][j], 0, 0, 0);
                acc[i][j] = __builtin_amdgcn_mfma_f32_16x16x32_f16(al[i], bh[j], acc[i][j], 0, 0, 0);
            }
        __syncthreads();
    }
    #pragma unroll
    for (int i = 0; i < 2; ++i)
        #pragma unroll
        for (int j = 0; j < 2; ++j) {
            int gcol = n0 + wn + j * 16 + lr;
            #pragma unroll
            for (int r = 0; r < 4; ++r) {
                int grow = m0 + wm + i * 16 + lq * 4 + r;
                ps[(size_t)grow * FIVEH + gcol] = acc[i][j][r];
            }
        }
}

// fallback gate reads the PT layout (big_gemm now writes PT)
__global__ void gate_kernel(const float* __restrict__ PT,
                            const float* __restrict__ Etab,
                            const float* __restrict__ ps,
                            const float* __restrict__ bs,
                            const int* __restrict__ eidx,
                            float* __restrict__ h,
                            float* __restrict__ c,
                            _Float16* __restrict__ hhi,
                            _Float16* __restrict__ hlo,
                            int t) {
    int j = blockIdx.x * 256 + threadIdx.x;
    int b = blockIdx.y;
    const float* prow = PT + (((size_t)t * 256 + (j >> 2)) * 128 + b) * 24 + (j & 3);
    const float* erow = Etab + (size_t)eidx[b] * SIXH;
    const float* psr  = ps + (size_t)b * FIVEH;
    float g[5];
    #pragma unroll
    for (int k = 0; k < 5; ++k)
        g[k] = prow[k * 4] + erow[k * H + j] + psr[k * H + j] + bs[k * H + j];
    float pi5 = prow[5 * 4] + erow[5 * H + j];
    float ig = 1.f / (1.f + expf(-g[0]));
    float fg = 1.f / (1.f + expf(-g[1]));
    float mi = tanhf(g[2]);
    float og = 1.f / (1.f + expf(-g[3]));
    float hw = 1.f / (1.f + expf(-g[4]));
    float cv = c[b * H + j];
    float cn = ig * mi + fg * cv;
    float out = og * tanhf(cn);
    float hn = hw * out + (1.f - hw) * pi5;
    c[b * H + j] = cn;
    h[b * H + j] = hn;
    _Float16 hh = (_Float16)hn;
    hhi[b * H + j] = hh;
    hlo[b * H + j] = (_Float16)(hn - (float)hh);
}

__global__ void pred_kernel(const float* __restrict__ h,
                            const float* __restrict__ Wo,
                            const float* __restrict__ bo,
                            const int* __restrict__ labels,
                            float* __restrict__ dists,
                            float* __restrict__ comms,
                            int* __restrict__ eidx,
                            int t) {
    __shared__ float hsb[H];
    __shared__ float vals[256];
    __shared__ int   idxs[256];
    int tid = threadIdx.x;
    int b = blockIdx.x;
    for (int i = tid; i < H / 4; i += 256)
        *(float4*)&hsb[i * 4] = *(const float4*)&h[b * H + i * 4];
    __syncthreads();
    float pred = 0.f;
    if (tid < C) {
        pred = bo[tid];
        #pragma unroll 8
        for (int k = 0; k < H; ++k)
            pred = fmaf(hsb[k], Wo[k * C + tid], pred);
        dists[(size_t)(t * B + b) * C + tid] = pred;
    }
    vals[tid] = (tid >= 1 && tid < C) ? pred : -1e30f;
    idxs[tid] = tid;
    __syncthreads();
    for (int s = 128; s > 0; s >>= 1) {
        if (tid < s) {
            float v2 = vals[tid + s];
            int   i2 = idxs[tid + s];
            if (v2 > vals[tid] || (v2 == vals[tid] && i2 < idxs[tid])) {
                vals[tid] = v2;
                idxs[tid] = i2;
            }
        }
        __syncthreads();
    }
    if (tid == 0) {
        int nzp = idxs[0];
        int lt = labels[t * B + b];
        int comm = (lt == 0) ? nzp : lt;
        comms[t * B + b] = (float)comm;
        eidx[b] = comm + 1;
    }
}

extern "C" void kernel_launch(void* const* d_in, const int* in_sizes, int n_in,
                              void* d_out, int out_size, void* d_ws, size_t ws_size,
                              hipStream_t stream) {
    const float* X      = (const float*)d_in[0];
    const int*   labels = (const int*)  d_in[1];
    const float* embed  = (const float*)d_in[2];
    const float* Wi     = (const float*)d_in[3];
    const float* bi     = (const float*)d_in[4];
    const float* Ws     = (const float*)d_in[5];
    const float* bs     = (const float*)d_in[6];
    const float* Wo     = (const float*)d_in[7];
    const float* bo     = (const float*)d_in[8];

    // R11 footprint (ran OK). h-parity/hfp overlay in dead Xlo space.
    char* w = (char*)d_ws;
    float* PT     = (float*)w;              w += (size_t)T * B * SIXH * 4;      // 100.7 MB
    float* Etab   = (float*)w;              w += (size_t)NEMB * SIXH * 4;       //   3.7 MB
    float* ps     = (float*)w;              w += (size_t)B * FIVEH * 4;         //   2.6 MB (fallback)
    float* h      = (float*)w;              w += (size_t)B * H * 4;             // fallback
    float* c      = (float*)w;              w += (size_t)B * H * 4;             // fallback
    _Float16* hhi = (_Float16*)w;           w += (size_t)B * H * 2;             // parity-1 packed (zeroed)
    _Float16* hlo = (_Float16*)w;           w += (size_t)B * H * 2;
    int* eidx     = (int*)w;                w += 512;
    int* bar      = (int*)w;                w += 32768;                          // 256+32 flags x16 ints
    _Float16* Xhi = (_Float16*)w;           w += (size_t)T * B * KTOT * 2;      //  16.8 MB
    _Float16* Xlo = (_Float16*)w;           w += (size_t)T * B * KTOT * 2;      //  16.8 MB
    _Float16* WiThi = (_Float16*)w;         w += (size_t)SIXH * KTOT * 2;       //  25.2 MB
    _Float16* WiTlo = (_Float16*)w;         w += (size_t)SIXH * KTOT * 2;
    _Float16* WsThi = (_Float16*)w;         w += (size_t)FIVEH * H * 2;         //  10.5 MB
    _Float16* WsTlo = (_Float16*)w;         w += (size_t)FIVEH * H * 2;
    // overlay (1.5 MB in dead 16.8 MB Xlo; write-before-read inside fused_loop)
    _Float16* hhiA = (_Float16*)Xlo;
    _Float16* hloA = hhiA + (size_t)B * H;
    float* hfpA    = (float*)(hloA + (size_t)B * H);
    float* hfpB    = hfpA + (size_t)B * H;

    float* dists = (float*)d_out;
    float* comms = dists + (size_t)T * B * C;

    init_kernel<<<512, 256, 0, stream>>>(h, c, hhi, hlo, eidx, bar);
    cvt_x<<<(T * B * KTOT) / (256 * 4), 256, 0, stream>>>(X, Xhi, Xlo);
    cvt_wT<KTOT, SIXH><<<dim3(SIXH / 32, KTOT / 32), 256, 0, stream>>>(Wi, WiThi, WiTlo);
    cvt_wT<H, FIVEH><<<dim3(FIVEH / 32, H / 32), 256, 0, stream>>>(Ws, WsThi, WsTlo);
    etab_kernel<<<dim3(SIXH / 256, NEMB), 256, 0, stream>>>(embed, Wi, Etab);
    big_gemm_mfma<<<dim3(SIXH / 128, (T * B) / 128), 256, 0, stream>>>(Xhi, Xlo, WiThi, WiTlo, bi, PT);

    void* args[] = {(void*)&PT, (void*)&Etab, (void*)&bs, (void*)&WsThi, (void*)&WsTlo,
                    (void*)&hhiA, (void*)&hloA, (void*)&hhi, (void*)&hlo,
                    (void*)&hfpA, (void*)&hfpB, (void*)&Wo, (void*)&bo,
                    (void*)&labels, (void*)&dists, (void*)&comms,
                    (void*)&eidx, (void*)&bar};
    hipError_t err = hipLaunchCooperativeKernel((void*)fused_loop, dim3(NWGF), dim3(256),
                                                args, 0, stream);
    if (err != hipSuccess) {
        // fallback: per-timestep loop (PT-aware gate; legacy row-major h)
        for (int t = 0; t < T; ++t) {
            ps_mfma<<<dim3(FIVEH / 64, B / 64), 256, 0, stream>>>(hhi, hlo, WsThi, WsTlo, ps);
            gate_kernel<<<dim3(H / 256, B), 256, 0, stream>>>(PT, Etab, ps, bs, eidx, h, c, hhi, hlo, t);
            pred_kernel<<<B, 256, 0, stream>>>(h, Wo, bo, labels, dists, comms, eidx, t);
        }
    }
}

// Round 13
// 3425.571 us; speedup vs baseline: 2.9762x; 2.5505x over previous
//
#include <hip/hip_runtime.h>
#include <math.h>

#define H    1024
#define C    151
#define E    200
#define DIN  2048
#define T    32
#define B    128
#define SIXH  (6*H)   // 6144
#define FIVEH (5*H)   // 5120
#define KTOT  DIN     // 2048
#define NEMB  (C+1)   // 152
#define NWG   320     // persistent blocks; 320*16 = 5120 cols; 70KB LDS -> 2 WGs/CU
#define COLS  16      // ps columns per WG
#define GUARD (1 << 20)   // spin bailout: bounded wrong-answer beats container-killing hang

typedef _Float16 f16x8 __attribute__((ext_vector_type(8)));
typedef _Float16 f16x4 __attribute__((ext_vector_type(4)));
typedef float    f32x4 __attribute__((ext_vector_type(4)));

#define GLOAD_LDS16(g, l) __builtin_amdgcn_global_load_lds( \
    (const __attribute__((address_space(1))) unsigned int*)(g), \
    (__attribute__((address_space(3))) unsigned int*)(l), 16, 0, 0)

// ---- flag-array grid barrier (R3/R9/R10-verified chain), 320-WG variant ----
// R12 post-mortem: the ~24us/sync is mostly POST-FENCE COLD RE-READ of h/P/Etab
// at fabric latency with 1 wave/SIMD — not sync mechanics (R4) nor dirty volume
// (R7). This round keeps the verified 2-barrier dataflow and doubles TLP
// (2 WGs/CU) so the cold reads overlap. Threads 0-63 poll two slots (320>256).
__device__ __forceinline__ void gbar_arrive(int* slots, int tid) {
    __syncthreads();   // drains this WG's stores (vmcnt) before release RMW
    if (tid == 0)
        __hip_atomic_fetch_add(&slots[blockIdx.x * 16], 1,
                               __ATOMIC_ACQ_REL, __HIP_MEMORY_SCOPE_AGENT);
}
__device__ __forceinline__ void gbar_wait(int* slots, int tid, int val) {
    int ok, guard = 0;
    do {
        int v1 = __hip_atomic_load(&slots[tid * 16],
                                   __ATOMIC_RELAXED, __HIP_MEMORY_SCOPE_AGENT);
        int v2 = val;
        if (tid < NWG - 256)
            v2 = __hip_atomic_load(&slots[(256 + tid) * 16],
                                   __ATOMIC_RELAXED, __HIP_MEMORY_SCOPE_AGENT);
        ok = __syncthreads_and(v1 >= val && v2 >= val);
        if (!ok) __builtin_amdgcn_s_sleep(1);
    } while (!ok && ++guard < GUARD);
    __builtin_amdgcn_fence(__ATOMIC_ACQUIRE, "agent");
}

// ---------------- init: zero h, c, hhi, hlo, eidx, barrier slots ----------------
__global__ void init_kernel(float* h, float* c, _Float16* hhi, _Float16* hlo,
                            int* eidx, int* bar) {
    int i = blockIdx.x * blockDim.x + threadIdx.x;
    if (i < B * H) {
        h[i] = 0.f; c[i] = 0.f;
        hhi[i] = (_Float16)0.f; hlo[i] = (_Float16)0.f;
    }
    if (i < B) eidx[i] = 0;
    if (i < NWG * 16) bar[i] = 0;
}

// ---------------- X [4096][2048] fp32 -> hi/lo fp16 (same layout) ----------------
__global__ void cvt_x(const float* __restrict__ X, _Float16* __restrict__ hi,
                      _Float16* __restrict__ lo) {
    size_t i = ((size_t)blockIdx.x * 256 + threadIdx.x) * 4;
    float4 v = *(const float4*)(X + i);
    f16x4 h, l;
    h.x = (_Float16)v.x; l.x = (_Float16)(v.x - (float)h.x);
    h.y = (_Float16)v.y; l.y = (_Float16)(v.y - (float)h.y);
    h.z = (_Float16)v.z; l.z = (_Float16)(v.z - (float)h.z);
    h.w = (_Float16)v.w; l.w = (_Float16)(v.w - (float)h.w);
    *(f16x4*)(hi + i) = h;
    *(f16x4*)(lo + i) = l;
}

// ---------------- W [KR][NC] fp32 -> out [NC][KR] hi/lo fp16 (transposed) ----------------
template<int KR, int NC>
__global__ void cvt_wT(const float* __restrict__ W, _Float16* __restrict__ hi,
                       _Float16* __restrict__ lo) {
    __shared__ float tile[32][33];
    int n0 = blockIdx.x * 32, k0 = blockIdx.y * 32;
    int tx = threadIdx.x & 31, ty = threadIdx.x >> 5;   // ty 0..7
    #pragma unroll
    for (int i = 0; i < 4; ++i) {
        int k = ty + i * 8;
        tile[k][tx] = W[(size_t)(k0 + k) * NC + n0 + tx];
    }
    __syncthreads();
    #pragma unroll
    for (int i = 0; i < 4; ++i) {
        int n = ty + i * 8;
        float v = tile[tx][n];              // = W[k0+tx][n0+n]
        _Float16 h = (_Float16)v;
        size_t o = (size_t)(n0 + n) * KR + k0 + tx;
        hi[o] = h;
        lo[o] = (_Float16)(v - (float)h);
    }
}

// ---------------- Wo [H][C] fp32 -> WoT [C][H] ----------------
__global__ void cvt_woT(const float* __restrict__ Wo, float* __restrict__ WoT) {
    int k = blockIdx.x * 256 + threadIdx.x;  // 0..H-1
    for (int c = 0; c < C; ++c)
        WoT[(size_t)c * H + k] = Wo[(size_t)k * C + c];
}

// ---------------- Etab[k][n] = sum_e embed[k][e] * Wi[DIN+e][n]  (fp32) ----------------
__global__ void etab_kernel(const float* __restrict__ embed,
                            const float* __restrict__ Wi,
                            float* __restrict__ Etab) {
    int n = blockIdx.x * 256 + threadIdx.x;
    int k = blockIdx.y;
    const float* wp = Wi + (size_t)DIN * SIXH + n;
    const float* ep = embed + k * E;
    float acc = 0.f;
    #pragma unroll 8
    for (int e = 0; e < E; ++e)
        acc = fmaf(ep[e], wp[(size_t)e * SIXH], acc);
    Etab[(size_t)k * SIXH + n] = acc;
}

// ---------------- P = X @ Wi_x + bi, fp16x3 MFMA. tile 128x128, 4 waves x 64x64 ----------
__global__ __launch_bounds__(256) void big_gemm_mfma(
    const _Float16* __restrict__ Ahi, const _Float16* __restrict__ Alo,
    const _Float16* __restrict__ Bhi, const _Float16* __restrict__ Blo,
    const float* __restrict__ bi, float* __restrict__ P)
{
    __shared__ __align__(16) _Float16 sAh[128 * 32];
    __shared__ __align__(16) _Float16 sAl[128 * 32];
    __shared__ __align__(16) _Float16 sBh[128 * 32];
    __shared__ __align__(16) _Float16 sBl[128 * 32];
    const int tid = threadIdx.x;
    const int n0 = blockIdx.x * 128;
    const int m0 = blockIdx.y * 128;
    const int lane = tid & 63, w = tid >> 6;
    const int wm = (w >> 1) * 64, wn = (w & 1) * 64;
    const int lr = lane & 15, lq = lane >> 4;

    f32x4 acc[4][4];
    #pragma unroll
    for (int i = 0; i < 4; ++i)
        #pragma unroll
        for (int j = 0; j < 4; ++j)
            acc[i][j] = (f32x4){0.f, 0.f, 0.f, 0.f};

    const int row0 = tid >> 2;        // 0..63
    const int kc = tid & 3;
    const int kcs = kc ^ ((row0 >> 1) & 3);   // swizzled source chunk
    const int sw = (lq ^ ((lr >> 1) & 3)) * 8; // swizzled read slot (halves)

    for (int k0 = 0; k0 < KTOT; k0 += 32) {
        #pragma unroll
        for (int i = 0; i < 2; ++i) {
            int row = row0 + i * 64;
            size_t ga = (size_t)(m0 + row) * KTOT + k0 + kcs * 8;
            size_t gb = (size_t)(n0 + row) * KTOT + k0 + kcs * 8;
            int loff = (i * 256 + tid) * 8;        // halves (linear dest)
            GLOAD_LDS16(Ahi + ga, sAh + loff);
            GLOAD_LDS16(Alo + ga, sAl + loff);
            GLOAD_LDS16(Bhi + gb, sBh + loff);
            GLOAD_LDS16(Blo + gb, sBl + loff);
        }
        __syncthreads();
        f16x8 ah[4], al[4], bh[4], bl[4];
        #pragma unroll
        for (int i = 0; i < 4; ++i) {
            ah[i] = *(const f16x8*)&sAh[(wm + i * 16 + lr) * 32 + sw];
            al[i] = *(const f16x8*)&sAl[(wm + i * 16 + lr) * 32 + sw];
            bh[i] = *(const f16x8*)&sBh[(wn + i * 16 + lr) * 32 + sw];
            bl[i] = *(const f16x8*)&sBl[(wn + i * 16 + lr) * 32 + sw];
        }
        #pragma unroll
        for (int i = 0; i < 4; ++i)
            #pragma unroll
            for (int j = 0; j < 4; ++j) {
                acc[i][j] = __builtin_amdgcn_mfma_f32_16x16x32_f16(ah[i], bh[j], acc[i][j], 0, 0, 0);
                acc[i][j] = __builtin_amdgcn_mfma_f32_16x16x32_f16(ah[i], bl[j], acc[i][j], 0, 0, 0);
                acc[i][j] = __builtin_amdgcn_mfma_f32_16x16x32_f16(al[i], bh[j], acc[i][j], 0, 0, 0);
            }
        __syncthreads();
    }
    #pragma unroll
    for (int i = 0; i < 4; ++i)
        #pragma unroll
        for (int j = 0; j < 4; ++j) {
            int gcol = n0 + wn + j * 16 + lr;
            float bv = bi[gcol];
            #pragma unroll
            for (int r = 0; r < 4; ++r) {
                int grow = m0 + wm + i * 16 + lq * 4 + r;
                P[(size_t)grow * SIXH + gcol] = acc[i][j][r] + bv;
            }
        }
}

// ================= persistent fused timestep loop (cooperative launch) =================
// R10-verified dataflow (2 barriers/step, pred in barrier-B wait-slack), with
// COLS=16 / NWG=320 -> 70KB LDS -> 2 WGs/CU (2 waves/SIMD) to hide the
// post-fence cold-read latency that dominates the step time.
__global__ __launch_bounds__(256, 2) void fused_loop(
    const float* __restrict__ P,
    const float* __restrict__ Etab,
    const float* __restrict__ bs,
    const _Float16* __restrict__ WsThi,
    const _Float16* __restrict__ WsTlo,
    _Float16* __restrict__ hhi,
    _Float16* __restrict__ hlo,
    float* __restrict__ ps,
    const float* __restrict__ WoT,
    const float* __restrict__ bo,
    const int* __restrict__ labels,
    float* __restrict__ dists,
    float* __restrict__ comms,
    int* bar)
{
    __shared__ __align__(16) _Float16 sBh[COLS * H];   // 32 KB, XOR-swizzled
    __shared__ __align__(16) _Float16 sBl[COLS * H];   // 32 KB
    __shared__ __align__(16) float hs[H];              // 4 KB (h_new row for pred)
    __shared__ float vals[256];
    __shared__ int   idxs[256];
    __shared__ int   s_eidx;

    const int wg  = blockIdx.x;
    const int tid = threadIdx.x;
    const int n0  = wg * COLS;
    const int lane = tid & 63, w = tid >> 6;
    const int lr = lane & 15, lq = lane >> 4;

    // ---- stage Ws slice into LDS, swizzled: granule byte ^= (col&7)<<4 ----
    for (int gi = tid; gi < COLS * (H / 8); gi += 256) {
        int col = gi >> 7;          // 128 granules of 16B per col
        int kg  = gi & 127;
        int dst = (col * (H * 2) + kg * 16) ^ ((col & 7) << 4);   // bytes
        *(f16x8*)((char*)sBh + dst) = *(const f16x8*)&WsThi[(size_t)(n0 + col) * H + kg * 8];
        *(f16x8*)((char*)sBl + dst) = *(const f16x8*)&WsTlo[(size_t)(n0 + col) * H + kg * 8];
    }

    float creg[4] = {0.f, 0.f, 0.f, 0.f};   // c-state, j = jj*256 + tid
    float bsr[4][5];
    if (wg < B) {
        #pragma unroll
        for (int jj = 0; jj < 4; ++jj)
            #pragma unroll
            for (int k = 0; k < 5; ++k)
                bsr[jj][k] = bs[k * H + jj * 256 + tid];
    }
    if (tid == 0) s_eidx = 0;
    __syncthreads();     // local staging done; cross-WG inputs are stream-ordered

    const int mrow0 = w * 32;
    int bval = 0;

    for (int t = 0; t < T; ++t) {
        int eidx_cur = s_eidx;     // feedback embedding index for this step

        // ---------- phase 1: ps[:, n0:n0+16] = (h) @ Ws-slice, fp16x3 ----------
        f32x4 acc[2];
        acc[0] = (f32x4){0.f, 0.f, 0.f, 0.f};
        acc[1] = (f32x4){0.f, 0.f, 0.f, 0.f};

        #pragma unroll 4
        for (int k0 = 0; k0 < H; k0 += 32) {
            f16x8 ah[2], al[2], bh, bl;
            #pragma unroll
            for (int i = 0; i < 2; ++i) {
                size_t ho = (size_t)(mrow0 + i * 16 + lr) * H + k0 + lq * 8;
                ah[i] = *(const f16x8*)&hhi[ho];
                al[i] = *(const f16x8*)&hlo[ho];
            }
            {
                int col = lr;
                int off = (col * (H * 2) + (k0 + lq * 8) * 2) ^ ((col & 7) << 4);
                bh = *(const f16x8*)((const char*)sBh + off);
                bl = *(const f16x8*)((const char*)sBl + off);
            }
            #pragma unroll
            for (int i = 0; i < 2; ++i) {
                acc[i] = __builtin_amdgcn_mfma_f32_16x16x32_f16(ah[i], bh, acc[i], 0, 0, 0);
                acc[i] = __builtin_amdgcn_mfma_f32_16x16x32_f16(ah[i], bl, acc[i], 0, 0, 0);
                acc[i] = __builtin_amdgcn_mfma_f32_16x16x32_f16(al[i], bh, acc[i], 0, 0, 0);
            }
        }
        #pragma unroll
        for (int i = 0; i < 2; ++i)
            #pragma unroll
            for (int r = 0; r < 4; ++r)
                ps[(size_t)(mrow0 + i * 16 + lq * 4 + r) * FIVEH + n0 + lr] = acc[i][r];

        // ---- T14 prefetch: P-row (cold HBM) + Etab-row into regs; latency hides
        // under barrier arrival/poll. Independent of ps/h, so legal pre-barrier. ----
        float pf[4][6], pe[4][6];
        if (wg < B) {
            const float* prow = P + (size_t)(t * B + wg) * SIXH;
            const float* erow = Etab + (size_t)eidx_cur * SIXH;
            #pragma unroll
            for (int jj = 0; jj < 4; ++jj)
                #pragma unroll
                for (int k = 0; k < 6; ++k) {
                    pf[jj][k] = prow[k * H + jj * 256 + tid];
                    pe[jj][k] = erow[k * H + jj * 256 + tid];
                }
        }

        ++bval;
        gbar_arrive(bar, tid);
        gbar_wait(bar, tid, bval);

        // ---------- phase 2: gate for b = wg; then arrive; pred/argmax in wait-slack ----
        if (wg < B) {
            const int b = wg;
            const float* psr = ps + (size_t)b * FIVEH;
            #pragma unroll
            for (int jj = 0; jj < 4; ++jj) {
                int j = jj * 256 + tid;
                float gv[5];
                #pragma unroll
                for (int k = 0; k < 5; ++k)
                    gv[k] = pf[jj][k] + pe[jj][k] + psr[k * H + j] + bsr[jj][k];
                float pi5 = pf[jj][5] + pe[jj][5];
                float ig = 1.f / (1.f + expf(-gv[0]));
                float fg = 1.f / (1.f + expf(-gv[1]));
                float mi = tanhf(gv[2]);
                float og = 1.f / (1.f + expf(-gv[3]));
                float hw = 1.f / (1.f + expf(-gv[4]));
                float cn = ig * mi + fg * creg[jj];
                float out = og * tanhf(cn);
                float hn = hw * out + (1.f - hw) * pi5;
                creg[jj] = cn;
                hs[j] = hn;
                _Float16 hh = (_Float16)hn;
                hhi[(size_t)b * H + j] = hh;
                hlo[(size_t)b * H + j] = (_Float16)(hn - (float)hh);
            }
        }
        // arrive releases h(t); its __syncthreads also publishes hs[] WG-locally
        ++bval;
        gbar_arrive(bar, tid);

        if (wg < B) {
            // ---- pred + argmax: purely WG-local; runs in this WG's wait-slack ----
            const int b = wg;
            float predv = 0.f;
            if (tid < C) {
                const float* wp = WoT + (size_t)tid * H;
                float a0 = bo[tid], a1 = 0.f, a2 = 0.f, a3 = 0.f;
                #pragma unroll 4
                for (int k = 0; k < H; k += 4) {
                    float4 w4 = *(const float4*)&wp[k];
                    float4 h4 = *(const float4*)&hs[k];
                    a0 = fmaf(h4.x, w4.x, a0);
                    a1 = fmaf(h4.y, w4.y, a1);
                    a2 = fmaf(h4.z, w4.z, a2);
                    a3 = fmaf(h4.w, w4.w, a3);
                }
                predv = (a0 + a1) + (a2 + a3);
                dists[(size_t)(t * B + b) * C + tid] = predv;
            }
            vals[tid] = (tid >= 1 && tid < C) ? predv : -1e30f;
            idxs[tid] = tid;
            __syncthreads();
            for (int s = 128; s > 0; s >>= 1) {
                if (tid < s) {
                    float v2 = vals[tid + s];
                    int   i2 = idxs[tid + s];
                    if (v2 > vals[tid] || (v2 == vals[tid] && i2 < idxs[tid])) {
                        vals[tid] = v2;
                        idxs[tid] = i2;
                    }
                }
                __syncthreads();
            }
            if (tid == 0) {
                int nzp = idxs[0];
                int lt = labels[t * B + b];
                int comm = (lt == 0) ? nzp : lt;
                comms[t * B + b] = (float)comm;
                s_eidx = comm + 1;   // read next step after gbar_wait's syncthreads
            }
        }
        gbar_wait(bar, tid, bval);
    }
}

// ================= fallback per-timestep kernels (used only if coop launch fails) =====
__global__ __launch_bounds__(256) void ps_mfma(
    const _Float16* __restrict__ Ahi, const _Float16* __restrict__ Alo,
    const _Float16* __restrict__ Bhi, const _Float16* __restrict__ Blo,
    float* __restrict__ ps)
{
    __shared__ __align__(16) _Float16 sAh[64 * 32];
    __shared__ __align__(16) _Float16 sAl[64 * 32];
    __shared__ __align__(16) _Float16 sBh[64 * 32];
    __shared__ __align__(16) _Float16 sBl[64 * 32];
    const int tid = threadIdx.x;
    const int n0 = blockIdx.x * 64;
    const int m0 = blockIdx.y * 64;
    const int lane = tid & 63, w = tid >> 6;
    const int wm = (w >> 1) * 32, wn = (w & 1) * 32;
    const int lr = lane & 15, lq = lane >> 4;

    f32x4 acc[2][2];
    #pragma unroll
    for (int i = 0; i < 2; ++i)
        #pragma unroll
        for (int j = 0; j < 2; ++j)
            acc[i][j] = (f32x4){0.f, 0.f, 0.f, 0.f};

    const int row = tid >> 2;
    const int kc = tid & 3;

    for (int k0 = 0; k0 < H; k0 += 32) {
        size_t ga = (size_t)(m0 + row) * H + k0 + kc * 8;
        size_t gb = (size_t)(n0 + row) * H + k0 + kc * 8;
        int loff = tid * 8;
        GLOAD_LDS16(Ahi + ga, sAh + loff);
        GLOAD_LDS16(Alo + ga, sAl + loff);
        GLOAD_LDS16(Bhi + gb, sBh + loff);
        GLOAD_LDS16(Blo + gb, sBl + loff);
        __syncthreads();
        f16x8 ah[2], al[2], bh[2], bl[2];
        #pragma unroll
        for (int i = 0; i < 2; ++i) {
            ah[i] = *(const f16x8*)&sAh[(wm + i * 16 + lr) * 32 + lq * 8];
            al[i] = *(const f16x8*)&sAl[(wm + i * 16 + lr) * 32 + lq * 8];
            bh[i] = *(const f16x8*)&sBh[(wn + i * 16 + lr) * 32 + lq * 8];
            bl[i] = *(const f16x8*)&sBl[(wn + i * 16 + lr) * 32 + lq * 8];
        }
        #pragma unroll
        for (int i = 0; i < 2; ++i)
            #pragma unroll
            for (int j = 0; j < 2; ++j) {
                acc[i][j] = __builtin_amdgcn_mfma_f32_16x16x32_f16(ah[i], bh[j], acc[i][j], 0, 0, 0);
                acc[i][j] = __builtin_amdgcn_mfma_f32_16x16x32_f16(ah[i], bl[j], acc[i][j], 0, 0, 0);
                acc[i][j] = __builtin_amdgcn_mfma_f32_16x16x32_f16(al[i], bh[j], acc[i][j], 0, 0, 0);
            }
        __syncthreads();
    }
    #pragma unroll
    for (int i = 0; i < 2; ++i)
        #pragma unroll
        for (int j = 0; j < 2; ++j) {
            int gcol = n0 + wn + j * 16 + lr;
            #pragma unroll
            for (int r = 0; r < 4; ++r) {
                int grow = m0 + wm + i * 16 + lq * 4 + r;
                ps[(size_t)grow * FIVEH + gcol] = acc[i][j][r];
            }
        }
}

__global__ void gate_kernel(const float* __restrict__ P,
                            const float* __restrict__ Etab,
                            const float* __restrict__ ps,
                            const float* __restrict__ bs,
                            const int* __restrict__ eidx,
                            float* __restrict__ h,
                            float* __restrict__ c,
                            _Float16* __restrict__ hhi,
                            _Float16* __restrict__ hlo,
                            int t) {
    int j = blockIdx.x * 256 + threadIdx.x;
    int b = blockIdx.y;
    const float* prow = P + (size_t)(t * B + b) * SIXH;
    const float* erow = Etab + (size_t)eidx[b] * SIXH;
    const float* psr  = ps + (size_t)b * FIVEH;
    float g[5];
    #pragma unroll
    for (int k = 0; k < 5; ++k) {
        int col = k * H + j;
        g[k] = prow[col] + erow[col] + psr[col] + bs[col];
    }
    float pi5 = prow[5 * H + j] + erow[5 * H + j];
    float ig = 1.f / (1.f + expf(-g[0]));
    float fg = 1.f / (1.f + expf(-g[1]));
    float mi = tanhf(g[2]);
    float og = 1.f / (1.f + expf(-g[3]));
    float hw = 1.f / (1.f + expf(-g[4]));
    float cv = c[b * H + j];
    float cn = ig * mi + fg * cv;
    float out = og * tanhf(cn);
    float hn = hw * out + (1.f - hw) * pi5;
    c[b * H + j] = cn;
    h[b * H + j] = hn;
    _Float16 hh = (_Float16)hn;
    hhi[b * H + j] = hh;
    hlo[b * H + j] = (_Float16)(hn - (float)hh);
}

__global__ void pred_kernel(const float* __restrict__ h,
                            const float* __restrict__ Wo,
                            const float* __restrict__ bo,
                            const int* __restrict__ labels,
                            float* __restrict__ dists,
                            float* __restrict__ comms,
                            int* __restrict__ eidx,
                            int t) {
    __shared__ float hsb[H];
    __shared__ float vals[256];
    __shared__ int   idxs[256];
    int tid = threadIdx.x;
    int b = blockIdx.x;
    for (int i = tid; i < H / 4; i += 256)
        *(float4*)&hsb[i * 4] = *(const float4*)&h[b * H + i * 4];
    __syncthreads();
    float pred = 0.f;
    if (tid < C) {
        pred = bo[tid];
        #pragma unroll 8
        for (int k = 0; k < H; ++k)
            pred = fmaf(hsb[k], Wo[k * C + tid], pred);
        dists[(size_t)(t * B + b) * C + tid] = pred;
    }
    vals[tid] = (tid >= 1 && tid < C) ? pred : -1e30f;
    idxs[tid] = tid;
    __syncthreads();
    for (int s = 128; s > 0; s >>= 1) {
        if (tid < s) {
            float v2 = vals[tid + s];
            int   i2 = idxs[tid + s];
            if (v2 > vals[tid] || (v2 == vals[tid] && i2 < idxs[tid])) {
                vals[tid] = v2;
                idxs[tid] = i2;
            }
        }
        __syncthreads();
    }
    if (tid == 0) {
        int nzp = idxs[0];
        int lt = labels[t * B + b];
        int comm = (lt == 0) ? nzp : lt;
        comms[t * B + b] = (float)comm;
        eidx[b] = comm + 1;
    }
}

extern "C" void kernel_launch(void* const* d_in, const int* in_sizes, int n_in,
                              void* d_out, int out_size, void* d_ws, size_t ws_size,
                              hipStream_t stream) {
    const float* X      = (const float*)d_in[0];
    const int*   labels = (const int*)  d_in[1];
    const float* embed  = (const float*)d_in[2];
    const float* Wi     = (const float*)d_in[3];
    const float* bi     = (const float*)d_in[4];
    const float* Ws     = (const float*)d_in[5];
    const float* bs     = (const float*)d_in[6];
    const float* Wo     = (const float*)d_in[7];
    const float* bo     = (const float*)d_in[8];

    // R3/R9 layout; bar enlarged to 32KB for 320 flag slots (R11/R12 ran this size).
    char* w = (char*)d_ws;
    float* P      = (float*)w;              w += (size_t)T * B * SIXH * 4;      // 100.7 MB
    float* Etab   = (float*)w;              w += (size_t)NEMB * SIXH * 4;       //   3.7 MB
    float* ps     = (float*)w;              w += (size_t)B * FIVEH * 4;         //   2.6 MB
    float* h      = (float*)w;              w += (size_t)B * H * 4;
    float* c      = (float*)w;              w += (size_t)B * H * 4;
    _Float16* hhi = (_Float16*)w;           w += (size_t)B * H * 2;
    _Float16* hlo = (_Float16*)w;           w += (size_t)B * H * 2;
    int* eidx     = (int*)w;                w += 512;
    int* bar      = (int*)w;                w += 32768;                          // NWG*16 flags (padded)
    _Float16* Xhi = (_Float16*)w;           w += (size_t)T * B * KTOT * 2;      //  16.8 MB
    _Float16* Xlo = (_Float16*)w;           w += (size_t)T * B * KTOT * 2;
    _Float16* WiThi = (_Float16*)w;         w += (size_t)SIXH * KTOT * 2;       //  25.2 MB
    _Float16* WiTlo = (_Float16*)w;         w += (size_t)SIXH * KTOT * 2;
    _Float16* WsThi = (_Float16*)w;         w += (size_t)FIVEH * H * 2;         //  10.5 MB
    _Float16* WsTlo = (_Float16*)w;         w += (size_t)FIVEH * H * 2;
    // WoT aliases Xhi (Xhi/Xlo dead after big_gemm; cvt_woT runs after big_gemm)
    float* WoT    = (float*)Xhi;

    float* dists = (float*)d_out;
    float* comms = dists + (size_t)T * B * C;

    init_kernel<<<512, 256, 0, stream>>>(h, c, hhi, hlo, eidx, bar);
    cvt_x<<<(T * B * KTOT) / (256 * 4), 256, 0, stream>>>(X, Xhi, Xlo);
    cvt_wT<KTOT, SIXH><<<dim3(SIXH / 32, KTOT / 32), 256, 0, stream>>>(Wi, WiThi, WiTlo);
    cvt_wT<H, FIVEH><<<dim3(FIVEH / 32, H / 32), 256, 0, stream>>>(Ws, WsThi, WsTlo);
    etab_kernel<<<dim3(SIXH / 256, NEMB), 256, 0, stream>>>(embed, Wi, Etab);
    big_gemm_mfma<<<dim3(SIXH / 128, (T * B) / 128), 256, 0, stream>>>(Xhi, Xlo, WiThi, WiTlo, bi, P);
    cvt_woT<<<dim3(H / 256), 256, 0, stream>>>(Wo, WoT);   // after big_gemm: Xhi space reused

    void* args[] = {(void*)&P, (void*)&Etab, (void*)&bs, (void*)&WsThi, (void*)&WsTlo,
                    (void*)&hhi, (void*)&hlo, (void*)&ps, (void*)&WoT, (void*)&bo,
                    (void*)&labels, (void*)&dists, (void*)&comms, (void*)&bar};
    hipError_t err = hipLaunchCooperativeKernel((void*)fused_loop, dim3(NWG), dim3(256),
                                                args, 0, stream);
    if (err != hipSuccess) {
        // fallback: original per-timestep loop
        for (int t = 0; t < T; ++t) {
            ps_mfma<<<dim3(FIVEH / 64, B / 64), 256, 0, stream>>>(hhi, hlo, WsThi, WsTlo, ps);
            gate_kernel<<<dim3(H / 256, B), 256, 0, stream>>>(P, Etab, ps, bs, eidx, h, c, hhi, hlo, t);
            pred_kernel<<<B, 256, 0, stream>>>(h, Wo, bo, labels, dists, comms, eidx, t);
        }
    }
}